// Round 5
// baseline (397.052 us; speedup 1.0000x reference)
//
#include <hip/hip_runtime.h>

static constexpr int N_NODES = 50000;
static constexpr int N_EDGES = 1600000;
static constexpr int CIN = 32;
static constexpr int HID = 64;
static constexpr int SBLK = 256;
static constexpr int NBLK = (N_NODES + SBLK - 1) / SBLK;   // 196

__device__ __forceinline__ unsigned short f2bf(float f) {
    unsigned int u = __float_as_uint(f);
    u = (u + 0x7fffu + ((u >> 16) & 1u)) >> 16;   // round-to-nearest-even
    return (unsigned short)u;
}
__device__ __forceinline__ float bfhi(unsigned int u) { return __uint_as_float(u & 0xffff0000u); }
__device__ __forceinline__ float bflo(unsigned int u) { return __uint_as_float(u << 16); }

// ---------------- CSR build ----------------

__global__ void hist_kernel(const int* __restrict__ ei, int* __restrict__ deg) {
    int i = blockIdx.x * blockDim.x + threadIdx.x;
    if (i < N_EDGES) atomicAdd(&deg[ei[N_EDGES + i]], 1);
}

__global__ void scan1_kernel(const int* __restrict__ deg, int* __restrict__ part) {
    __shared__ int red[4];
    const int i = blockIdx.x * SBLK + threadIdx.x;
    int v = (i < N_NODES) ? deg[i] : 0;
#pragma unroll
    for (int m = 32; m > 0; m >>= 1) v += __shfl_xor(v, m);
    if ((threadIdx.x & 63) == 0) red[threadIdx.x >> 6] = v;
    __syncthreads();
    if (threadIdx.x == 0) part[blockIdx.x] = red[0] + red[1] + red[2] + red[3];
}

__global__ void scan2_kernel(int* __restrict__ part) {
    __shared__ int s[SBLK];
    const int t = threadIdx.x;
    const int v = (t < NBLK) ? part[t] : 0;
    s[t] = v;
    __syncthreads();
    for (int st = 1; st < SBLK; st <<= 1) {
        int u = (t >= st) ? s[t - st] : 0;
        __syncthreads();
        s[t] += u;
        __syncthreads();
    }
    if (t < NBLK) part[t] = s[t] - v;
}

__global__ void scan3_kernel(const int* __restrict__ deg, const int* __restrict__ part,
                             int* __restrict__ off, int* __restrict__ cursor) {
    __shared__ int s[SBLK];
    const int i = blockIdx.x * SBLK + threadIdx.x;
    const int t = threadIdx.x;
    const int v = (i < N_NODES) ? deg[i] : 0;
    s[t] = v;
    __syncthreads();
    for (int st = 1; st < SBLK; st <<= 1) {
        int u = (t >= st) ? s[t - st] : 0;
        __syncthreads();
        s[t] += u;
        __syncthreads();
    }
    const int excl = s[t] - v + part[blockIdx.x];
    if (i < N_NODES) { off[i] = excl; cursor[i] = excl; }
    if (i == N_NODES - 1) off[N_NODES] = N_EDGES;
}

__global__ void scatter_kernel(const int* __restrict__ ei,
                               int* __restrict__ cursor,
                               int* __restrict__ sorted_src) {
    int i = blockIdx.x * blockDim.x + threadIdx.x;
    if (i < N_EDGES) {
        const int d = ei[N_EDGES + i];
        const int pos = atomicAdd(&cursor[d], 1);
        sorted_src[pos] = ei[i];
    }
}

// ---------------- x -> bf16 transcode ----------------
__global__ void xcast_kernel(const float* __restrict__ x, unsigned short* __restrict__ xb) {
    const int i = blockIdx.x * 256 + threadIdx.x;     // 4 floats per thread
    if (i < N_NODES * CIN / 4) {
        const float4 v = reinterpret_cast<const float4*>(x)[i];
        uint2 o;
        o.x = (unsigned)f2bf(v.x) | ((unsigned)f2bf(v.y) << 16);
        o.y = (unsigned)f2bf(v.z) | ((unsigned)f2bf(v.w) << 16);
        reinterpret_cast<uint2*>(xb)[i] = o;
    }
}

// ---------------- layer 0 ----------------
// wave per node; bf16 x rows (64B): 4 lanes/row, 16 edges per gather instr.
// grp = lane>>2 (edge slot 0..15), cg = lane&3 (channels 8cg..8cg+7).
__global__ void __launch_bounds__(256)
layer0_kernel(const float* __restrict__ x,
              const unsigned short* __restrict__ xb,
              const int* __restrict__ off,
              const int* __restrict__ src,
              const float* __restrict__ Wl,
              const float* __restrict__ Wr,
              const float* __restrict__ b,
              float* __restrict__ h,
              unsigned short* __restrict__ hb) {
    const int node = blockIdx.x * 4 + (threadIdx.x >> 6);
    const int lane = threadIdx.x & 63;
    if (node >= N_NODES) return;
    const int e0 = off[node], e1 = off[node + 1];
    const int deg = e1 - e0;
    const int grp = lane >> 2;
    const int cg  = lane & 3;

    // hoisted independent loads
    const int cg8 = lane & 7;
    const float4 xs = *reinterpret_cast<const float4*>(x + (size_t)node * CIN + cg8 * 4);
    const float bias = b[lane];

    float a[8] = {0,0,0,0,0,0,0,0};
    for (int base = e0; base < e1; base += 64) {
        const int cnt = min(64, e1 - base);
        const int p = base + lane;
        const int sidx = (p < e1) ? src[p] : 0;
        const int nb = (cnt + 15) >> 4;
        uint4 u[4];
#pragma unroll
        for (int t = 0; t < 4; ++t) u[t] = make_uint4(0u, 0u, 0u, 0u);
#pragma unroll
        for (int t = 0; t < 4; ++t) {            // load phase: all gathers issued
            if (t < nb) {
                const int pos = (t << 4) | grp;
                const int s = __shfl(sidx, pos);
                if (pos < cnt)
                    u[t] = *reinterpret_cast<const uint4*>(xb + (size_t)s * CIN + cg * 8);
            }
        }
#pragma unroll
        for (int t = 0; t < 4; ++t) {            // add phase (zeros are no-ops)
            a[0] += bflo(u[t].x); a[1] += bfhi(u[t].x);
            a[2] += bflo(u[t].y); a[3] += bfhi(u[t].y);
            a[4] += bflo(u[t].z); a[5] += bfhi(u[t].z);
            a[6] += bflo(u[t].w); a[7] += bfhi(u[t].w);
        }
    }
    // reduce across grp (lane bits 2..5)
#pragma unroll
    for (int j = 0; j < 8; ++j) {
        a[j] += __shfl_xor(a[j], 4);
        a[j] += __shfl_xor(a[j], 8);
        a[j] += __shfl_xor(a[j], 16);
        a[j] += __shfl_xor(a[j], 32);
    }
    const float inv = 1.0f / fmaxf((float)deg, 1.0f);
#pragma unroll
    for (int j = 0; j < 8; ++j) a[j] *= inv;     // mean for channel 8*cg + j

    const float x4[4] = {xs.x, xs.y, xs.z, xs.w};
    float oA = bias, oB = 0.f, oC = 0.f, oD = 0.f;
#pragma unroll
    for (int k = 0; k < CIN; k += 2) {
        const float mk0 = __shfl(a[k & 7], k >> 3);
        const float xk0 = __shfl(x4[k & 3], k >> 2);
        const float mk1 = __shfl(a[(k + 1) & 7], (k + 1) >> 3);
        const float xk1 = __shfl(x4[(k + 1) & 3], (k + 1) >> 2);
        oA = fmaf(mk0, Wl[k * HID + lane], oA);
        oB = fmaf(xk0, Wr[k * HID + lane], oB);
        oC = fmaf(mk1, Wl[(k + 1) * HID + lane], oC);
        oD = fmaf(xk1, Wr[(k + 1) * HID + lane], oD);
    }
    const float o = (oA + oB) + (oC + oD);
    float ss = o * o;
#pragma unroll
    for (int m = 32; m > 0; m >>= 1) ss += __shfl_xor(ss, m);
    const float v = o / fmaxf(sqrtf(ss), 1e-12f);
    const float vr = fmaxf(v, 0.0f);
    h[(size_t)node * HID + lane] = vr;
    hb[(size_t)node * HID + lane] = f2bf(vr);
}

// ---------------- layer 1 + classifier ----------------
// bf16 h rows (128B): 8 lanes/row, 8 edges per gather instr.
// grp = lane>>3 (edge slot 0..7), cg = lane&7 (channels 8cg..8cg+7).
__global__ void __launch_bounds__(256)
layer1_kernel(const float* __restrict__ h,
              const unsigned short* __restrict__ hb,
              const int* __restrict__ off,
              const int* __restrict__ src,
              const float* __restrict__ Wl,
              const float* __restrict__ Wr,
              const float* __restrict__ b,
              const float* __restrict__ Wc1,
              const float* __restrict__ bc1,
              const float* __restrict__ Wc2,
              const float* __restrict__ bc2,
              float* __restrict__ out) {
    const int node = blockIdx.x * 4 + (threadIdx.x >> 6);
    const int lane = threadIdx.x & 63;
    if (node >= N_NODES) return;
    const int e0 = off[node], e1 = off[node + 1];
    const int deg = e1 - e0;
    const int grp = lane >> 3;
    const int cg  = lane & 7;

    const int cg16 = lane & 15;
    const float4 hs = *reinterpret_cast<const float4*>(h + (size_t)node * HID + cg16 * 4);
    const float bias = b[lane];

    float a[8] = {0,0,0,0,0,0,0,0};
    for (int base = e0; base < e1; base += 64) {
        const int cnt = min(64, e1 - base);
        const int p = base + lane;
        const int sidx = (p < e1) ? src[p] : 0;
        const int nb = (cnt + 7) >> 3;
        uint4 u[8];
#pragma unroll
        for (int t = 0; t < 8; ++t) u[t] = make_uint4(0u, 0u, 0u, 0u);
#pragma unroll
        for (int t = 0; t < 8; ++t) {            // load phase: up to 8 gathers in flight
            if (t < nb) {
                const int pos = (t << 3) | grp;
                const int s = __shfl(sidx, pos);
                if (pos < cnt)
                    u[t] = *reinterpret_cast<const uint4*>(hb + (size_t)s * HID + cg * 8);
            }
        }
#pragma unroll
        for (int t = 0; t < 8; ++t) {
            a[0] += bflo(u[t].x); a[1] += bfhi(u[t].x);
            a[2] += bflo(u[t].y); a[3] += bfhi(u[t].y);
            a[4] += bflo(u[t].z); a[5] += bfhi(u[t].z);
            a[6] += bflo(u[t].w); a[7] += bfhi(u[t].w);
        }
    }
    // reduce across grp (lane bits 3..5)
#pragma unroll
    for (int j = 0; j < 8; ++j) {
        a[j] += __shfl_xor(a[j], 8);
        a[j] += __shfl_xor(a[j], 16);
        a[j] += __shfl_xor(a[j], 32);
    }
    const float inv = 1.0f / fmaxf((float)deg, 1.0f);
#pragma unroll
    for (int j = 0; j < 8; ++j) a[j] *= inv;     // mean for channel 8*cg + j

    const float h4[4] = {hs.x, hs.y, hs.z, hs.w};
    float oA = bias, oB = 0.f, oC = 0.f, oD = 0.f;
#pragma unroll
    for (int k = 0; k < HID; k += 2) {
        const float mk0 = __shfl(a[k & 7], k >> 3);
        const float hk0 = __shfl(h4[k & 3], k >> 2);
        const float mk1 = __shfl(a[(k + 1) & 7], (k + 1) >> 3);
        const float hk1 = __shfl(h4[(k + 1) & 3], (k + 1) >> 2);
        oA = fmaf(mk0, Wl[k * HID + lane], oA);
        oB = fmaf(hk0, Wr[k * HID + lane], oB);
        oC = fmaf(mk1, Wl[(k + 1) * HID + lane], oC);
        oD = fmaf(hk1, Wr[(k + 1) * HID + lane], oD);
    }
    const float o = (oA + oB) + (oC + oD);
    float ss = o * o;
#pragma unroll
    for (int m = 32; m > 0; m >>= 1) ss += __shfl_xor(ss, m);
    const float v = o / fmaxf(sqrtf(ss), 1e-12f);   // normalized h2[lane]

    const int j = lane & 31;
    float cacc = bc1[j];
#pragma unroll
    for (int oo = 0; oo < HID; ++oo) {
        const float vo = __shfl(v, oo);
        cacc = fmaf(vo, Wc1[oo * 32 + j], cacc);
    }
    float partial = (lane < 32) ? fmaxf(cacc, 0.0f) * Wc2[j] : 0.0f;
#pragma unroll
    for (int m = 32; m > 0; m >>= 1) partial += __shfl_xor(partial, m);
    if (lane == 0) out[node] = partial + bc2[0];
}

extern "C" void kernel_launch(void* const* d_in, const int* in_sizes, int n_in,
                              void* d_out, int out_size, void* d_ws, size_t ws_size,
                              hipStream_t stream) {
    const float* x   = (const float*)d_in[0];
    const int*   ei  = (const int*)d_in[1];
    const float* Wl0 = (const float*)d_in[2];
    const float* b0  = (const float*)d_in[3];
    const float* Wr0 = (const float*)d_in[4];
    const float* Wl1 = (const float*)d_in[5];
    const float* b1  = (const float*)d_in[6];
    const float* Wr1 = (const float*)d_in[7];
    const float* Wc1 = (const float*)d_in[8];
    const float* bc1 = (const float*)d_in[9];
    const float* Wc2 = (const float*)d_in[10];
    const float* bc2 = (const float*)d_in[11];
    float* out = (float*)d_out;

    // ws layout (float-offsets, all 16B aligned)
    int*   deg        = (int*)d_ws;                                  // [0, 50000)
    int*   off        = deg + N_NODES;                               // 50001
    int*   cursor     = (int*)d_ws + 100016;                         // 50000
    int*   part       = (int*)d_ws + 150016;                         // NBLK
    int*   sorted_src = (int*)d_ws + 150224;                         // E
    float* h          = (float*)d_ws + 1750224;                      // N*64 f32
    unsigned short* xb = (unsigned short*)((float*)d_ws + 4950224);  // N*32 bf16
    unsigned short* hb = (unsigned short*)((float*)d_ws + 5750224);  // N*64 bf16

    hipMemsetAsync(deg, 0, N_NODES * sizeof(int), stream);

    const int T = 256;
    xcast_kernel<<<(N_NODES * CIN / 4 + T - 1) / T, T, 0, stream>>>(x, xb);
    hist_kernel<<<(N_EDGES + T - 1) / T, T, 0, stream>>>(ei, deg);
    scan1_kernel<<<NBLK, SBLK, 0, stream>>>(deg, part);
    scan2_kernel<<<1, SBLK, 0, stream>>>(part);
    scan3_kernel<<<NBLK, SBLK, 0, stream>>>(deg, part, off, cursor);
    scatter_kernel<<<(N_EDGES + T - 1) / T, T, 0, stream>>>(ei, cursor, sorted_src);

    const int ngrid = (N_NODES + 3) / 4;
    layer0_kernel<<<ngrid, T, 0, stream>>>(x, xb, off, sorted_src, Wl0, Wr0, b0, h, hb);
    layer1_kernel<<<ngrid, T, 0, stream>>>(h, hb, off, sorted_src, Wl1, Wr1, b1,
                                           Wc1, bc1, Wc2, bc2, out);
}

// Round 7
// 306.356 us; speedup vs baseline: 1.2960x; 1.2960x over previous
//
#include <hip/hip_runtime.h>

static constexpr int N_NODES = 50000;
static constexpr int N_EDGES = 1600000;
static constexpr int CIN = 32;
static constexpr int HID = 64;
static constexpr int SBLK = 256;
static constexpr int NBLK = (N_NODES + SBLK - 1) / SBLK;   // 196
static constexpr int NTB = N_NODES / 16;                   // 3125 transform blocks

__device__ __forceinline__ unsigned short f2bf(float f) {
    unsigned int u = __float_as_uint(f);
    u = (u + 0x7fffu + ((u >> 16) & 1u)) >> 16;   // RNE
    return (unsigned short)u;
}
__device__ __forceinline__ float bfhi(unsigned int u) { return __uint_as_float(u & 0xffff0000u); }
__device__ __forceinline__ float bflo(unsigned int u) { return __uint_as_float(u << 16); }

// ---------------- CSR build (R4-proven) ----------------

__global__ void hist_kernel(const int* __restrict__ ei, int* __restrict__ deg) {
    int i = blockIdx.x * blockDim.x + threadIdx.x;
    if (i < N_EDGES) atomicAdd(&deg[ei[N_EDGES + i]], 1);
}

__global__ void scan1_kernel(const int* __restrict__ deg, int* __restrict__ part) {
    __shared__ int red[4];
    const int i = blockIdx.x * SBLK + threadIdx.x;
    int v = (i < N_NODES) ? deg[i] : 0;
#pragma unroll
    for (int m = 32; m > 0; m >>= 1) v += __shfl_xor(v, m);
    if ((threadIdx.x & 63) == 0) red[threadIdx.x >> 6] = v;
    __syncthreads();
    if (threadIdx.x == 0) part[blockIdx.x] = red[0] + red[1] + red[2] + red[3];
}

__global__ void scan2_kernel(int* __restrict__ part) {
    __shared__ int s[SBLK];
    const int t = threadIdx.x;
    const int v = (t < NBLK) ? part[t] : 0;
    s[t] = v;
    __syncthreads();
    for (int st = 1; st < SBLK; st <<= 1) {
        int u = (t >= st) ? s[t - st] : 0;
        __syncthreads();
        s[t] += u;
        __syncthreads();
    }
    if (t < NBLK) part[t] = s[t] - v;
}

__global__ void scan3_kernel(const int* __restrict__ deg, const int* __restrict__ part,
                             int* __restrict__ off, int* __restrict__ cursor) {
    __shared__ int s[SBLK];
    const int i = blockIdx.x * SBLK + threadIdx.x;
    const int t = threadIdx.x;
    const int v = (i < N_NODES) ? deg[i] : 0;
    s[t] = v;
    __syncthreads();
    for (int st = 1; st < SBLK; st <<= 1) {
        int u = (t >= st) ? s[t - st] : 0;
        __syncthreads();
        s[t] += u;
        __syncthreads();
    }
    const int excl = s[t] - v + part[blockIdx.x];
    if (i < N_NODES) { off[i] = excl; cursor[i] = excl; }
    if (i == N_NODES - 1) off[N_NODES] = N_EDGES;
}

__global__ void scatter_kernel(const int* __restrict__ ei,
                               int* __restrict__ cursor,
                               int* __restrict__ sorted_src) {
    int i = blockIdx.x * blockDim.x + threadIdx.x;
    if (i < N_EDGES) {
        const int d = ei[N_EDGES + i];
        const int pos = atomicAdd(&cursor[d], 1);
        sorted_src[pos] = ei[i];
    }
}

// ---------------- agg0: mean of neighbor x rows (fp32 in, bf16 out) --------
// wave/node; 8 edge-slots x 8 lanes; lane: grp=lane>>3 slot, cg=lane&7 -> 4 ch.
__global__ void __launch_bounds__(256)
agg0_kernel(const float* __restrict__ x,
            const int* __restrict__ off, const int* __restrict__ src,
            unsigned short* __restrict__ mean0b) {
    const int node = blockIdx.x * 4 + (threadIdx.x >> 6);
    const int lane = threadIdx.x & 63;
    if (node >= N_NODES) return;
    const int e0 = off[node], e1 = off[node + 1];
    const int deg = e1 - e0;
    const int grp = lane >> 3, cg = lane & 7;

    float a[4] = {0, 0, 0, 0};
    for (int base = e0; base < e1; base += 64) {
        const int cnt = min(64, e1 - base);
        const int p = base + lane;
        const int sidx = (p < e1) ? src[p] : 0;
        const int nb = (cnt + 7) >> 3;
        float4 u[8];
#pragma unroll
        for (int t = 0; t < 8; ++t) u[t] = make_float4(0.f, 0.f, 0.f, 0.f);
#pragma unroll
        for (int t = 0; t < 8; ++t) {            // load phase
            if (t < nb) {
                const int pos = (t << 3) | grp;
                const int s = __shfl(sidx, pos);
                if (pos < cnt)
                    u[t] = *reinterpret_cast<const float4*>(x + (size_t)s * CIN + cg * 4);
            }
        }
#pragma unroll
        for (int t = 0; t < 8; ++t) {
            a[0] += u[t].x; a[1] += u[t].y; a[2] += u[t].z; a[3] += u[t].w;
        }
    }
#pragma unroll
    for (int j = 0; j < 4; ++j) {
        a[j] += __shfl_xor(a[j], 8);
        a[j] += __shfl_xor(a[j], 16);
        a[j] += __shfl_xor(a[j], 32);
    }
    const float inv = 1.0f / fmaxf((float)deg, 1.0f);
    if (grp == 0) {                              // lanes 0..7, channels 4cg..4cg+3
        uint2 o;
        o.x = (unsigned)f2bf(a[0] * inv) | ((unsigned)f2bf(a[1] * inv) << 16);
        o.y = (unsigned)f2bf(a[2] * inv) | ((unsigned)f2bf(a[3] * inv) << 16);
        reinterpret_cast<uint2*>(mean0b)[node * 8 + cg] = o;
    }
}

// ---------------- agg1: mean of neighbor h rows (bf16 in, fp32 out) --------
// 8 edge-slots x 8 lanes; cg=lane&7 -> 8 ch (bf16 uint4).
__global__ void __launch_bounds__(256)
agg1_kernel(const unsigned short* __restrict__ hb,
            const int* __restrict__ off, const int* __restrict__ src,
            float* __restrict__ mean1f) {
    const int node = blockIdx.x * 4 + (threadIdx.x >> 6);
    const int lane = threadIdx.x & 63;
    if (node >= N_NODES) return;
    const int e0 = off[node], e1 = off[node + 1];
    const int deg = e1 - e0;
    const int grp = lane >> 3, cg = lane & 7;

    float a[8] = {0, 0, 0, 0, 0, 0, 0, 0};
    for (int base = e0; base < e1; base += 64) {
        const int cnt = min(64, e1 - base);
        const int p = base + lane;
        const int sidx = (p < e1) ? src[p] : 0;
        const int nb = (cnt + 7) >> 3;
        uint4 u[8];
#pragma unroll
        for (int t = 0; t < 8; ++t) u[t] = make_uint4(0u, 0u, 0u, 0u);
#pragma unroll
        for (int t = 0; t < 8; ++t) {
            if (t < nb) {
                const int pos = (t << 3) | grp;
                const int s = __shfl(sidx, pos);
                if (pos < cnt)
                    u[t] = *reinterpret_cast<const uint4*>(hb + (size_t)s * HID + cg * 8);
            }
        }
#pragma unroll
        for (int t = 0; t < 8; ++t) {
            a[0] += bflo(u[t].x); a[1] += bfhi(u[t].x);
            a[2] += bflo(u[t].y); a[3] += bfhi(u[t].y);
            a[4] += bflo(u[t].z); a[5] += bfhi(u[t].z);
            a[6] += bflo(u[t].w); a[7] += bfhi(u[t].w);
        }
    }
#pragma unroll
    for (int j = 0; j < 8; ++j) {
        a[j] += __shfl_xor(a[j], 8);
        a[j] += __shfl_xor(a[j], 16);
        a[j] += __shfl_xor(a[j], 32);
    }
    const float inv = 1.0f / fmaxf((float)deg, 1.0f);
    if (grp == 0) {                              // lanes 0..7, channels 8cg..8cg+7
        float4 o1 = make_float4(a[0] * inv, a[1] * inv, a[2] * inv, a[3] * inv);
        float4 o2 = make_float4(a[4] * inv, a[5] * inv, a[6] * inv, a[7] * inv);
        float4* dst = reinterpret_cast<float4*>(mean1f + (size_t)node * HID + cg * 8);
        dst[0] = o1; dst[1] = o2;
    }
}

// ---------------- transform 0: out = mean0@Wl0 + x@Wr0 + b0; L2norm; relu --
// block = 256 thr = 16 nodes; thread: node n = t>>4, channels 4cg..4cg+3.
__global__ void __launch_bounds__(256)
transform0_kernel(const float* __restrict__ x,
                  const unsigned short* __restrict__ mean0b,
                  const float* __restrict__ Wl0, const float* __restrict__ Wr0,
                  const float* __restrict__ b0,
                  unsigned short* __restrict__ hb) {
    __shared__ float sWl[CIN * HID];   // 8KB
    __shared__ float sWr[CIN * HID];   // 8KB
    __shared__ float sMin[16 * CIN];   // 2KB
    __shared__ float sXin[16 * CIN];   // 2KB
    const int t = threadIdx.x;
    const int blk = blockIdx.x;                       // nodes blk*16 ..
    // stage weights (2048 floats each = 512 float4)
    reinterpret_cast<float4*>(sWl)[t]       = reinterpret_cast<const float4*>(Wl0)[t];
    reinterpret_cast<float4*>(sWl)[t + 256] = reinterpret_cast<const float4*>(Wl0)[t + 256];
    reinterpret_cast<float4*>(sWr)[t]       = reinterpret_cast<const float4*>(Wr0)[t];
    reinterpret_cast<float4*>(sWr)[t + 256] = reinterpret_cast<const float4*>(Wr0)[t + 256];
    // stage mean0 (512 bf16 = 256 uint) and x (512 f32 = 128 float4)
    {
        const unsigned u = reinterpret_cast<const unsigned*>(mean0b)[blk * 256 + t];
        sMin[2 * t]     = bflo(u);
        sMin[2 * t + 1] = bfhi(u);
    }
    if (t < 128)
        reinterpret_cast<float4*>(sXin)[t] =
            reinterpret_cast<const float4*>(x + (size_t)blk * 16 * CIN)[t];
    __syncthreads();

    const int n = t >> 4, cg = t & 15;
    const float4 bv = reinterpret_cast<const float4*>(b0)[cg];
    float a[4] = {bv.x, bv.y, bv.z, bv.w};
#pragma unroll
    for (int k = 0; k < CIN; ++k) {
        const float m  = sMin[n * CIN + k];
        const float xx = sXin[n * CIN + k];
        const float4 wl = reinterpret_cast<const float4*>(sWl + k * HID)[cg];
        const float4 wr = reinterpret_cast<const float4*>(sWr + k * HID)[cg];
        a[0] = fmaf(m, wl.x, fmaf(xx, wr.x, a[0]));
        a[1] = fmaf(m, wl.y, fmaf(xx, wr.y, a[1]));
        a[2] = fmaf(m, wl.z, fmaf(xx, wr.z, a[2]));
        a[3] = fmaf(m, wl.w, fmaf(xx, wr.w, a[3]));
    }
    float ss = a[0] * a[0] + a[1] * a[1] + a[2] * a[2] + a[3] * a[3];
    ss += __shfl_xor(ss, 1);
    ss += __shfl_xor(ss, 2);
    ss += __shfl_xor(ss, 4);
    ss += __shfl_xor(ss, 8);
    const float sc = 1.0f / fmaxf(sqrtf(ss), 1e-12f);
    uint2 o;
    o.x = (unsigned)f2bf(fmaxf(a[0] * sc, 0.f)) | ((unsigned)f2bf(fmaxf(a[1] * sc, 0.f)) << 16);
    o.y = (unsigned)f2bf(fmaxf(a[2] * sc, 0.f)) | ((unsigned)f2bf(fmaxf(a[3] * sc, 0.f)) << 16);
    reinterpret_cast<uint2*>(hb)[(size_t)(blk * 16 + n) * 16 + cg] = o;
}

// ---------------- transform 1: sage layer1 + L2norm + classifier -> out ----
__global__ void __launch_bounds__(256)
transform1_kernel(const unsigned short* __restrict__ hb,
                  const float* __restrict__ mean1f,
                  const float* __restrict__ Wl1, const float* __restrict__ Wr1,
                  const float* __restrict__ b1,
                  const float* __restrict__ Wc1, const float* __restrict__ bc1,
                  const float* __restrict__ Wc2, const float* __restrict__ bc2,
                  float* __restrict__ out) {
    __shared__ float sWl[HID * HID];   // 16KB
    __shared__ float sWr[HID * HID];   // 16KB
    __shared__ float sWc[HID * 32];    // 8KB
    __shared__ float sMin[16 * HID];   // 4KB
    __shared__ float sHin[16 * HID];   // 4KB
    __shared__ float sV[16 * HID];     // 4KB
    const int t = threadIdx.x;
    const int blk = blockIdx.x;
#pragma unroll
    for (int i = 0; i < 4; ++i) {
        reinterpret_cast<float4*>(sWl)[t + 256 * i] = reinterpret_cast<const float4*>(Wl1)[t + 256 * i];
        reinterpret_cast<float4*>(sWr)[t + 256 * i] = reinterpret_cast<const float4*>(Wr1)[t + 256 * i];
    }
#pragma unroll
    for (int i = 0; i < 2; ++i)
        reinterpret_cast<float4*>(sWc)[t + 256 * i] = reinterpret_cast<const float4*>(Wc1)[t + 256 * i];
    // mean1 tile: 1024 f32 = 256 float4
    reinterpret_cast<float4*>(sMin)[t] =
        reinterpret_cast<const float4*>(mean1f + (size_t)blk * 16 * HID)[t];
    // h tile: 1024 bf16 = 256 uint2
    {
        const uint2 hu = reinterpret_cast<const uint2*>(hb)[(size_t)blk * 256 + t];
        sHin[4 * t]     = bflo(hu.x);
        sHin[4 * t + 1] = bfhi(hu.x);
        sHin[4 * t + 2] = bflo(hu.y);
        sHin[4 * t + 3] = bfhi(hu.y);
    }
    __syncthreads();

    const int n = t >> 4, cg = t & 15;
    const float4 bv = reinterpret_cast<const float4*>(b1)[cg];
    float a[4] = {bv.x, bv.y, bv.z, bv.w};
#pragma unroll
    for (int k = 0; k < HID; ++k) {
        const float m  = sMin[n * HID + k];
        const float hh = sHin[n * HID + k];
        const float4 wl = reinterpret_cast<const float4*>(sWl + k * HID)[cg];
        const float4 wr = reinterpret_cast<const float4*>(sWr + k * HID)[cg];
        a[0] = fmaf(m, wl.x, fmaf(hh, wr.x, a[0]));
        a[1] = fmaf(m, wl.y, fmaf(hh, wr.y, a[1]));
        a[2] = fmaf(m, wl.z, fmaf(hh, wr.z, a[2]));
        a[3] = fmaf(m, wl.w, fmaf(hh, wr.w, a[3]));
    }
    float ss = a[0] * a[0] + a[1] * a[1] + a[2] * a[2] + a[3] * a[3];
    ss += __shfl_xor(ss, 1);
    ss += __shfl_xor(ss, 2);
    ss += __shfl_xor(ss, 4);
    ss += __shfl_xor(ss, 8);
    const float sc = 1.0f / fmaxf(sqrtf(ss), 1e-12f);
    sV[n * HID + 4 * cg + 0] = a[0] * sc;   // normalized, no relu
    sV[n * HID + 4 * cg + 1] = a[1] * sc;
    sV[n * HID + 4 * cg + 2] = a[2] * sc;
    sV[n * HID + 4 * cg + 3] = a[3] * sc;
    __syncthreads();

    // classifier: thread handles hidden units cg and cg+16 of node n
    float c1a = bc1[cg], c1b = bc1[cg + 16];
#pragma unroll
    for (int k = 0; k < HID; ++k) {
        const float vv = sV[n * HID + k];
        c1a = fmaf(vv, sWc[k * 32 + cg], c1a);
        c1b = fmaf(vv, sWc[k * 32 + cg + 16], c1b);
    }
    float pp = fmaxf(c1a, 0.f) * Wc2[cg] + fmaxf(c1b, 0.f) * Wc2[cg + 16];
    pp += __shfl_xor(pp, 1);
    pp += __shfl_xor(pp, 2);
    pp += __shfl_xor(pp, 4);
    pp += __shfl_xor(pp, 8);
    if (cg == 0) out[blk * 16 + n] = pp + bc2[0];
}

extern "C" void kernel_launch(void* const* d_in, const int* in_sizes, int n_in,
                              void* d_out, int out_size, void* d_ws, size_t ws_size,
                              hipStream_t stream) {
    const float* x   = (const float*)d_in[0];
    const int*   ei  = (const int*)d_in[1];
    const float* Wl0 = (const float*)d_in[2];
    const float* b0  = (const float*)d_in[3];
    const float* Wr0 = (const float*)d_in[4];
    const float* Wl1 = (const float*)d_in[5];
    const float* b1  = (const float*)d_in[6];
    const float* Wr1 = (const float*)d_in[7];
    const float* Wc1 = (const float*)d_in[8];
    const float* bc1 = (const float*)d_in[9];
    const float* Wc2 = (const float*)d_in[10];
    const float* bc2 = (const float*)d_in[11];
    float* out = (float*)d_out;

    // ws layout (float offsets, 16B aligned); total 29.4MB (== R5 proven)
    float* W = (float*)d_ws;
    int*   deg        = (int*)W;                              // 50000
    int*   off        = (int*)(W + 50048);                    // 50001
    int*   cursor     = (int*)(W + 100064);                   // 50000
    int*   part       = (int*)(W + 150080);                   // 196
    int*   sorted_src = (int*)(W + 150400);                   // 1.6M
    unsigned short* mean0b = (unsigned short*)(W + 1750400);  // N*32 bf16
    unsigned short* hb     = (unsigned short*)(W + 2550400);  // N*64 bf16
    float*          mean1f = W + 4150400;                     // N*64 f32

    hipMemsetAsync(deg, 0, N_NODES * sizeof(int), stream);

    const int T = 256;
    hist_kernel<<<(N_EDGES + T - 1) / T, T, 0, stream>>>(ei, deg);
    scan1_kernel<<<NBLK, SBLK, 0, stream>>>(deg, part);
    scan2_kernel<<<1, SBLK, 0, stream>>>(part);
    scan3_kernel<<<NBLK, SBLK, 0, stream>>>(deg, part, off, cursor);
    scatter_kernel<<<(N_EDGES + T - 1) / T, T, 0, stream>>>(ei, cursor, sorted_src);

    const int ngrid = (N_NODES + 3) / 4;
    agg0_kernel<<<ngrid, T, 0, stream>>>(x, off, sorted_src, mean0b);
    transform0_kernel<<<NTB, T, 0, stream>>>(x, mean0b, Wl0, Wr0, b0, hb);
    agg1_kernel<<<ngrid, T, 0, stream>>>(hb, off, sorted_src, mean1f);
    transform1_kernel<<<NTB, T, 0, stream>>>(hb, mean1f, Wl1, Wr1, b1,
                                             Wc1, bc1, Wc2, bc2, out);
}